// Round 4
// baseline (141.692 us; speedup 1.0000x reference)
//
#include <hip/hip_runtime.h>
#include <math.h>

#define NB 4
#define NS 2048
#define NF 256
#define NH 8
#define ND 32

constexpr float LN_EPS = 1e-3f;
constexpr float QSCALE = 0.35355339059327373f; // 1/sqrt(H)
constexpr float LOG2E  = 1.4426950408889634f;

typedef __bf16 bf16x8 __attribute__((ext_vector_type(8)));
typedef float f32x4 __attribute__((ext_vector_type(4)));

// ---------------------------------------------------------------------------
// Pre-pass A: x fp32 -> bf16
// ---------------------------------------------------------------------------
__global__ __launch_bounds__(256)
void cvt_x(const float* __restrict__ x, unsigned short* __restrict__ xb)
{
    const int i = (blockIdx.x * 256 + threadIdx.x) * 8;
    float4 a = *(const float4*)(x + i);
    float4 b = *(const float4*)(x + i + 4);
    union { ushort4 u; __bf16 h[4]; } o0, o1;
    o0.h[0] = (__bf16)a.x; o0.h[1] = (__bf16)a.y; o0.h[2] = (__bf16)a.z; o0.h[3] = (__bf16)a.w;
    o1.h[0] = (__bf16)b.x; o1.h[1] = (__bf16)b.y; o1.h[2] = (__bf16)b.z; o1.h[3] = (__bf16)b.w;
    *(ushort4*)(xb + i) = o0.u;
    *(ushort4*)(xb + i + 4) = o1.u;
}

// ---------------------------------------------------------------------------
// Pre-pass B: W[k][n] fp32 -> Wt[n][k] bf16.
// z=0: Wq (scaled by QSCALE*LOG2E), z=1: Wk, z=2: Wv, z=3: Wf.
// ---------------------------------------------------------------------------
__global__ __launch_bounds__(256)
void prep_w(const float* __restrict__ Wq, const float* __restrict__ Wk,
            const float* __restrict__ Wv, const float* __restrict__ Wf,
            unsigned short* __restrict__ wt)
{
    const int z = blockIdx.z;
    const float* W = (z == 0) ? Wq : (z == 1) ? Wk : (z == 2) ? Wv : Wf;
    const float scale = (z == 0) ? QSCALE * LOG2E : 1.0f;
    const int r0 = blockIdx.y * 64, c0 = blockIdx.x * 64;
    const int t = threadIdx.x;
    const int tr = t >> 4, tc4 = (t & 15) * 4;

    __shared__ float tile[64][65];
    #pragma unroll
    for (int p = 0; p < 4; ++p) {
        float4 v = *(const float4*)(W + (size_t)(r0 + tr + p * 16) * NF + c0 + tc4);
        tile[tr + p * 16][tc4 + 0] = v.x;
        tile[tr + p * 16][tc4 + 1] = v.y;
        tile[tr + p * 16][tc4 + 2] = v.z;
        tile[tr + p * 16][tc4 + 3] = v.w;
    }
    __syncthreads();
    #pragma unroll
    for (int p = 0; p < 4; ++p) {
        union { ushort4 u; __bf16 h[4]; } o;
        #pragma unroll
        for (int j = 0; j < 4; ++j)
            o.h[j] = (__bf16)(tile[tc4 + j][tr + p * 16] * scale);
        *(ushort4*)(wt + (size_t)z * 65536 + (size_t)(c0 + tr + p * 16) * NF + r0 + tc4) = o.u;
    }
}

// ---------------------------------------------------------------------------
// Kernel 1: QKV projection, bf16 MFMA.  Block = 64 rows x 256 cols, 4 waves.
// Q/K written [B,H,S,D]; V written TRANSPOSED [B,H,D,S] for direct PV loads.
// ---------------------------------------------------------------------------
__global__ __launch_bounds__(256)
void qkv_mfma(const unsigned short* __restrict__ xb, const unsigned short* __restrict__ wt,
              unsigned short* __restrict__ qo, unsigned short* __restrict__ ko,
              unsigned short* __restrict__ vo)
{
    const int z = blockIdx.y;
    unsigned short* out = (z == 0) ? qo : (z == 1) ? ko : vo;
    const unsigned short* W = wt + (size_t)z * 65536;

    const int r0 = blockIdx.x * 64;
    const int t = threadIdx.x;
    const int w = t >> 6, lane = t & 63;
    const int l15 = lane & 15, lhi = lane >> 4;
    const int wr = w >> 1, wc = w & 1;

    f32x4 acc[2][8] = {};

    for (int kt = 0; kt < NF; kt += 32) {
        bf16x8 a0 = *(const bf16x8*)(xb + (size_t)(r0 + wr * 32 + l15) * NF + kt + lhi * 8);
        bf16x8 a1 = *(const bf16x8*)(xb + (size_t)(r0 + wr * 32 + 16 + l15) * NF + kt + lhi * 8);
        #pragma unroll
        for (int c = 0; c < 8; ++c) {
            bf16x8 b = *(const bf16x8*)(W + (size_t)(wc * 128 + c * 16 + l15) * NF + kt + lhi * 8);
            acc[0][c] = __builtin_amdgcn_mfma_f32_16x16x32_bf16(a0, b, acc[0][c], 0, 0, 0);
            acc[1][c] = __builtin_amdgcn_mfma_f32_16x16x32_bf16(a1, b, acc[1][c], 0, 0, 0);
        }
    }

    #pragma unroll
    for (int i = 0; i < 2; ++i) {
        #pragma unroll
        for (int c = 0; c < 8; ++c) {
            const int col = wc * 128 + c * 16 + l15;
            const int h = col >> 5, d = col & 31;
            const int rowbase = r0 + wr * 32 + i * 16 + lhi * 4;
            const int b = rowbase >> 11, s = rowbase & 2047;
            if (z == 2) {
                // V^T: 4 consecutive s for fixed d -> contiguous ushort4
                union { ushort4 u; __bf16 h4[4]; } o;
                #pragma unroll
                for (int r = 0; r < 4; ++r) o.h4[r] = (__bf16)acc[i][c][r];
                *(ushort4*)(out + ((size_t)(b * NH + h) * ND + d) * NS + s) = o.u;
            } else {
                #pragma unroll
                for (int r = 0; r < 4; ++r) {
                    __bf16 o = (__bf16)acc[i][c][r];
                    out[((size_t)(b * NH + h) * NS + (s + r)) * ND + d] = *(unsigned short*)&o;
                }
            }
        }
    }
}

// ---------------------------------------------------------------------------
// Kernel 2: flash attention, no-max softmax (log2e pre-folded into Wq).
// Block = 4 waves x 16 q-rows; NO barriers in the main loop:
//   - P per-wave in LDS, K direct global (regs, prefetched),
//   - V read directly from global V^T (prefetched) -> no V staging.
// l is a pure running sum, reduced once at the end.  ctx written bf16.
// ---------------------------------------------------------------------------
__global__ __launch_bounds__(256)
void attn_mfma(const unsigned short* __restrict__ q, const unsigned short* __restrict__ k,
               const unsigned short* __restrict__ vt, unsigned short* __restrict__ ctxb)
{
    const int bh = blockIdx.x;            // all s-tiles of a bh land on XCD bh%8
    const int s0 = blockIdx.y * 64;
    const int t = threadIdx.x;
    const int w = t >> 6;
    const int lane = t & 63;
    const int l15 = lane & 15;
    const int lhi = lane >> 4;

    __shared__ unsigned short ps[4][16][72];   // per-wave P [q=l15][key]

    const unsigned short* qb  = q  + (size_t)bh * NS * ND;
    const unsigned short* kb  = k  + (size_t)bh * NS * ND;
    const unsigned short* vtb = vt + (size_t)bh * ND * NS;   // V^T [d][s]

    // Q B-operand fragment (scores pre-scaled to log2 domain via Wq)
    bf16x8 qfrag = *(const bf16x8*)(qb + (size_t)(s0 + w * 16 + l15) * ND + lhi * 8);

    float lpart = 0.0f;                    // running sum for q = l15 (partial)
    f32x4 acc0 = {0.f, 0.f, 0.f, 0.f};    // ctx[q=lhi*4+r][d=l15]
    f32x4 acc1 = {0.f, 0.f, 0.f, 0.f};    // d = 16+l15

    bf16x8 kf[4], kn[4], vlo[2], vhi[2], vnlo[2], vnhi[2];
    #pragma unroll
    for (int f = 0; f < 4; ++f)
        kf[f] = *(const bf16x8*)(kb + (size_t)(f * 16 + l15) * ND + lhi * 8);
    #pragma unroll
    for (int c = 0; c < 2; ++c) {
        vlo[c] = *(const bf16x8*)(vtb + (size_t)l15 * NS        + c * 32 + lhi * 8);
        vhi[c] = *(const bf16x8*)(vtb + (size_t)(16 + l15) * NS + c * 32 + lhi * 8);
    }

    for (int tI = 0; tI < 32; ++tI) {
        const int ktn = ((tI + 1) & 31) * 64;
        #pragma unroll
        for (int f = 0; f < 4; ++f)
            kn[f] = *(const bf16x8*)(kb + (size_t)(ktn + f * 16 + l15) * ND + lhi * 8);
        #pragma unroll
        for (int c = 0; c < 2; ++c) {
            vnlo[c] = *(const bf16x8*)(vtb + (size_t)l15 * NS        + ktn + c * 32 + lhi * 8);
            vnhi[c] = *(const bf16x8*)(vtb + (size_t)(16 + l15) * NS + ktn + c * 32 + lhi * 8);
        }

        // QK^T swapped: sc[f][r] = S[key=f*16+lhi*4+r][q=l15] (log2 domain)
        const f32x4 zero = {0.f, 0.f, 0.f, 0.f};
        f32x4 sc[4];
        __builtin_amdgcn_s_setprio(1);
        #pragma unroll
        for (int f = 0; f < 4; ++f)
            sc[f] = __builtin_amdgcn_mfma_f32_16x16x32_bf16(kf[f], qfrag, zero, 0, 0, 0);
        __builtin_amdgcn_s_setprio(0);

        // no-max softmax: p = 2^score, accumulate l, pack P to LDS
        #pragma unroll
        for (int f = 0; f < 4; ++f) {
            float p0 = __builtin_amdgcn_exp2f(sc[f][0]);
            float p1 = __builtin_amdgcn_exp2f(sc[f][1]);
            float p2 = __builtin_amdgcn_exp2f(sc[f][2]);
            float p3 = __builtin_amdgcn_exp2f(sc[f][3]);
            lpart += (p0 + p1) + (p2 + p3);
            union { ushort4 u; __bf16 h[4]; } pk;
            pk.h[0] = (__bf16)p0; pk.h[1] = (__bf16)p1;
            pk.h[2] = (__bf16)p2; pk.h[3] = (__bf16)p3;
            *(ushort4*)&ps[w][l15][f * 16 + lhi * 4] = pk.u;
        }

        // PV: acc += P[16q x 64k] * V[64k x 32d]  (V direct from regs)
        __builtin_amdgcn_s_setprio(1);
        #pragma unroll
        for (int c = 0; c < 2; ++c) {
            bf16x8 pa = *(const bf16x8*)&ps[w][l15][c * 32 + lhi * 8];
            acc0 = __builtin_amdgcn_mfma_f32_16x16x32_bf16(pa, vlo[c], acc0, 0, 0, 0);
            acc1 = __builtin_amdgcn_mfma_f32_16x16x32_bf16(pa, vhi[c], acc1, 0, 0, 0);
        }
        __builtin_amdgcn_s_setprio(0);

        #pragma unroll
        for (int f = 0; f < 4; ++f) kf[f] = kn[f];
        #pragma unroll
        for (int c = 0; c < 2; ++c) { vlo[c] = vnlo[c]; vhi[c] = vnhi[c]; }
    }

    // final l reduction (once): sum the 4 lhi partials for each q=l15
    lpart += __shfl_xor(lpart, 16);
    lpart += __shfl_xor(lpart, 32);

    const int b = bh >> 3, h = bh & 7;
    #pragma unroll
    for (int r = 0; r < 4; ++r) {
        float li = __shfl(lpart, lhi * 4 + r);
        float inv = 1.0f / li;
        int row = s0 + w * 16 + lhi * 4 + r;
        unsigned short* op = ctxb + ((size_t)b * NS + row) * NF + h * ND;
        __bf16 o0 = (__bf16)(acc0[r] * inv);
        __bf16 o1 = (__bf16)(acc1[r] * inv);
        op[l15]      = *(unsigned short*)&o0;
        op[16 + l15] = *(unsigned short*)&o1;
    }
}

// ---------------------------------------------------------------------------
// Kernel 3: y = relu(ctx @ Wf + bf); z = x + y; out = LayerNorm(z).
// bf16 MFMA GEMM (32 rows x 256 cols per block, 4 waves each 64 cols),
// LN fused via LDS z-tile + wave shuffle reductions.
// ---------------------------------------------------------------------------
__global__ __launch_bounds__(256)
void dense_ln(const unsigned short* __restrict__ ctxb, const unsigned short* __restrict__ wft,
              const float* __restrict__ bfp, const float* __restrict__ x,
              float* __restrict__ out)
{
    const int r0 = blockIdx.x * 32;
    const int t = threadIdx.x;
    const int w = t >> 6;
    const int lane = t & 63;
    const int l15 = lane & 15;
    const int lhi = lane >> 4;

    __shared__ float zs[32][258];

    f32x4 acc[2][4] = {};

    for (int kt = 0; kt < NF; kt += 32) {
        bf16x8 a0 = *(const bf16x8*)(ctxb + (size_t)(r0 + l15) * NF + kt + lhi * 8);
        bf16x8 a1 = *(const bf16x8*)(ctxb + (size_t)(r0 + 16 + l15) * NF + kt + lhi * 8);
        #pragma unroll
        for (int c = 0; c < 4; ++c) {
            bf16x8 b = *(const bf16x8*)(wft + (size_t)(w * 64 + c * 16 + l15) * NF + kt + lhi * 8);
            acc[0][c] = __builtin_amdgcn_mfma_f32_16x16x32_bf16(a0, b, acc[0][c], 0, 0, 0);
            acc[1][c] = __builtin_amdgcn_mfma_f32_16x16x32_bf16(a1, b, acc[1][c], 0, 0, 0);
        }
    }

    // stage y = relu(acc + bias) into LDS
    #pragma unroll
    for (int i = 0; i < 2; ++i) {
        #pragma unroll
        for (int c = 0; c < 4; ++c) {
            const int col = w * 64 + c * 16 + l15;
            const float bb = bfp[col];
            #pragma unroll
            for (int r = 0; r < 4; ++r) {
                const int row = i * 16 + lhi * 4 + r;
                zs[row][col] = fmaxf(acc[i][c][r] + bb, 0.0f);
            }
        }
    }
    __syncthreads();

    // LN: wave w handles rows w*8 .. w*8+7; residual added here (vectorized)
    #pragma unroll
    for (int i = 0; i < 8; ++i) {
        const int row = w * 8 + i;
        float4 yv = *(const float4*)&zs[row][lane * 4];
        float4 xv = *(const float4*)(x + (size_t)(r0 + row) * NF + lane * 4);
        float z0 = xv.x + yv.x, z1 = xv.y + yv.y;
        float z2 = xv.z + yv.z, z3 = xv.w + yv.w;
        float sum = z0 + z1 + z2 + z3;
        float sq  = z0*z0 + z1*z1 + z2*z2 + z3*z3;
        #pragma unroll
        for (int o = 1; o < 64; o <<= 1) {
            sum += __shfl_xor(sum, o);
            sq  += __shfl_xor(sq, o);
        }
        float mean = sum * (1.0f / NF);
        float var  = sq * (1.0f / NF) - mean * mean;
        float rstd = rsqrtf(var + LN_EPS);
        float4 o4;
        o4.x = (z0 - mean) * rstd;
        o4.y = (z1 - mean) * rstd;
        o4.z = (z2 - mean) * rstd;
        o4.w = (z3 - mean) * rstd;
        *(float4*)(out + (size_t)(r0 + row) * NF + lane * 4) = o4;
    }
}

// ---------------------------------------------------------------------------
extern "C" void kernel_launch(void* const* d_in, const int* in_sizes, int n_in,
                              void* d_out, int out_size, void* d_ws, size_t ws_size,
                              hipStream_t stream)
{
    const float* x  = (const float*)d_in[0];
    const float* Wq = (const float*)d_in[1];
    const float* Wk = (const float*)d_in[2];
    const float* Wv = (const float*)d_in[3];
    const float* Wf = (const float*)d_in[4];
    const float* bf = (const float*)d_in[5];
    float* out = (float*)d_out;

    const size_t per = (size_t)NB * NH * NS * ND;   // 2M elements
    unsigned short* q    = (unsigned short*)d_ws;
    unsigned short* kk   = q + per;
    unsigned short* vvt  = kk + per;                // V^T [B,H,D,S]
    unsigned short* xb   = vvt + per;
    unsigned short* wt   = xb + per;                // 4 * 64K bf16 (Wq,Wk,Wv,Wf)
    unsigned short* ctxb = wt + 4 * 65536;          // bf16 [B*S][F]

    cvt_x<<<dim3((int)(per / (8 * 256))), 256, 0, stream>>>(x, xb);
    prep_w<<<dim3(4, 4, 4), 256, 0, stream>>>(Wq, Wk, Wv, Wf, wt);
    qkv_mfma<<<dim3(128, 3), 256, 0, stream>>>(xb, wt, q, kk, vvt);
    attn_mfma<<<dim3(NB * NH, NS / 64), 256, 0, stream>>>(q, kk, vvt, ctxb);
    dense_ln<<<dim3((NB * NS) / 32), 256, 0, stream>>>(ctxb, wt + 3 * 65536, bf, x, out);
}

// Round 5
// 88.885 us; speedup vs baseline: 1.5941x; 1.5941x over previous
//
#include <hip/hip_runtime.h>
#include <math.h>

#define NB 4
#define NS 2048
#define NF 256
#define NH 8
#define ND 32

constexpr float LN_EPS = 1e-3f;
constexpr float QSCALE = 0.35355339059327373f; // 1/sqrt(H)
constexpr float LOG2E  = 1.4426950408889634f;

typedef __bf16 bf16x8 __attribute__((ext_vector_type(8)));
typedef float f32x4 __attribute__((ext_vector_type(4)));

// ---------------------------------------------------------------------------
// Pre-pass (merged): blocks 0..1023 convert x fp32->bf16 (8 elems/thread);
// blocks 1024..1087 transpose W[k][n] -> Wt[n][k] bf16.
// z=0: Wq (scaled QSCALE*LOG2E), z=1: Wk, z=2: Wv, z=3: Wf.
// ---------------------------------------------------------------------------
__global__ __launch_bounds__(256)
void prep(const float* __restrict__ x, const float* __restrict__ Wq,
          const float* __restrict__ Wk, const float* __restrict__ Wv,
          const float* __restrict__ Wf, unsigned short* __restrict__ xb,
          unsigned short* __restrict__ wt)
{
    __shared__ float tile[64][65];
    const int id = blockIdx.x;
    const int t = threadIdx.x;

    if (id < 1024) {
        const int i = (id * 256 + t) * 8;
        float4 a = *(const float4*)(x + i);
        float4 b = *(const float4*)(x + i + 4);
        union { ushort4 u; __bf16 h[4]; } o0, o1;
        o0.h[0] = (__bf16)a.x; o0.h[1] = (__bf16)a.y; o0.h[2] = (__bf16)a.z; o0.h[3] = (__bf16)a.w;
        o1.h[0] = (__bf16)b.x; o1.h[1] = (__bf16)b.y; o1.h[2] = (__bf16)b.z; o1.h[3] = (__bf16)b.w;
        *(ushort4*)(xb + i) = o0.u;
        *(ushort4*)(xb + i + 4) = o1.u;
        return;
    }

    const int wid = id - 1024;          // 0..63
    const int z = wid >> 4;             // 0..3
    const int tl = wid & 15;
    const float* W = (z == 0) ? Wq : (z == 1) ? Wk : (z == 2) ? Wv : Wf;
    const float scale = (z == 0) ? QSCALE * LOG2E : 1.0f;
    const int r0 = (tl >> 2) * 64, c0 = (tl & 3) * 64;
    const int tr = t >> 4, tc4 = (t & 15) * 4;

    #pragma unroll
    for (int p = 0; p < 4; ++p) {
        float4 v = *(const float4*)(W + (size_t)(r0 + tr + p * 16) * NF + c0 + tc4);
        tile[tr + p * 16][tc4 + 0] = v.x;
        tile[tr + p * 16][tc4 + 1] = v.y;
        tile[tr + p * 16][tc4 + 2] = v.z;
        tile[tr + p * 16][tc4 + 3] = v.w;
    }
    __syncthreads();
    #pragma unroll
    for (int p = 0; p < 4; ++p) {
        union { ushort4 u; __bf16 h[4]; } o;
        #pragma unroll
        for (int j = 0; j < 4; ++j)
            o.h[j] = (__bf16)(tile[tc4 + j][tr + p * 16] * scale);
        *(ushort4*)(wt + (size_t)z * 65536 + (size_t)(c0 + tr + p * 16) * NF + r0 + tc4) = o.u;
    }
}

// ---------------------------------------------------------------------------
// Kernel 1: QKV projection, bf16 MFMA.  Block = 64 rows x 256 cols, 4 waves.
// All outputs row-major [B,H,S,D].
// ---------------------------------------------------------------------------
__global__ __launch_bounds__(256)
void qkv_mfma(const unsigned short* __restrict__ xb, const unsigned short* __restrict__ wt,
              unsigned short* __restrict__ qo, unsigned short* __restrict__ ko,
              unsigned short* __restrict__ vo)
{
    const int z = blockIdx.y;
    unsigned short* out = (z == 0) ? qo : (z == 1) ? ko : vo;
    const unsigned short* W = wt + (size_t)z * 65536;

    const int r0 = blockIdx.x * 64;
    const int t = threadIdx.x;
    const int w = t >> 6, lane = t & 63;
    const int l15 = lane & 15, lhi = lane >> 4;
    const int wr = w >> 1, wc = w & 1;

    f32x4 acc[2][8] = {};

    for (int kt = 0; kt < NF; kt += 32) {
        bf16x8 a0 = *(const bf16x8*)(xb + (size_t)(r0 + wr * 32 + l15) * NF + kt + lhi * 8);
        bf16x8 a1 = *(const bf16x8*)(xb + (size_t)(r0 + wr * 32 + 16 + l15) * NF + kt + lhi * 8);
        #pragma unroll
        for (int c = 0; c < 8; ++c) {
            bf16x8 b = *(const bf16x8*)(W + (size_t)(wc * 128 + c * 16 + l15) * NF + kt + lhi * 8);
            acc[0][c] = __builtin_amdgcn_mfma_f32_16x16x32_bf16(a0, b, acc[0][c], 0, 0, 0);
            acc[1][c] = __builtin_amdgcn_mfma_f32_16x16x32_bf16(a1, b, acc[1][c], 0, 0, 0);
        }
    }

    #pragma unroll
    for (int i = 0; i < 2; ++i) {
        #pragma unroll
        for (int c = 0; c < 8; ++c) {
            const int col = wc * 128 + c * 16 + l15;
            const int h = col >> 5, d = col & 31;
            #pragma unroll
            for (int r = 0; r < 4; ++r) {
                const int row = r0 + wr * 32 + i * 16 + lhi * 4 + r;
                const int b = row >> 11, s = row & 2047;
                __bf16 o = (__bf16)acc[i][c][r];
                out[((size_t)(b * NH + h) * NS + s) * ND + d] = *(unsigned short*)&o;
            }
        }
    }
}

// ---------------------------------------------------------------------------
// Kernel 2: flash attention, no-max softmax (log2e folded into Wq upstream).
// Round-3 structure: block = 4 waves x 16 q-rows of one (b,h); KV tile = 64.
//   - K fragments one tile ahead in regs (coalesced 64B-segment loads),
//   - V staged transposed into LDS (double-buffered, coalesced row loads),
//   - P per-wave in LDS, ONE barrier per tile.
// l is a per-lane running sum, reduced once at the end.  ctx written bf16.
// ---------------------------------------------------------------------------
__global__ __launch_bounds__(256)
void attn_mfma(const unsigned short* __restrict__ q, const unsigned short* __restrict__ k,
               const unsigned short* __restrict__ v, unsigned short* __restrict__ ctxb)
{
    const int bh = blockIdx.x;            // all s-tiles of one bh share an XCD
    const int s0 = blockIdx.y * 64;
    const int t = threadIdx.x;
    const int w = t >> 6;
    const int lane = t & 63;
    const int l15 = lane & 15;
    const int lhi = lane >> 4;

    __shared__ unsigned short ps[4][16][72];   // per-wave P [q=l15][key]
    __shared__ unsigned short vt[2][32][72];   // V^T dbuf [d][key]

    const unsigned short* qb = q + (size_t)bh * NS * ND;
    const unsigned short* kb = k + (size_t)bh * NS * ND;
    const unsigned short* vb = v + (size_t)bh * NS * ND;

    // Q B-operand fragment (scores arrive in log2 domain via Wq scaling)
    bf16x8 qfrag = *(const bf16x8*)(qb + (size_t)(s0 + w * 16 + l15) * ND + lhi * 8);

    float lpart = 0.0f;                    // running denom partial for q=l15
    f32x4 acc0 = {0.f, 0.f, 0.f, 0.f};    // ctx[q=lhi*4+r][d=l15]
    f32x4 acc1 = {0.f, 0.f, 0.f, 0.f};    // d = 16+l15

    // ---- prologue: tile 0 ----
    bf16x8 kf[4], kn[4];
    #pragma unroll
    for (int f = 0; f < 4; ++f)
        kf[f] = *(const bf16x8*)(kb + (size_t)(f * 16 + l15) * ND + lhi * 8);
    {
        bf16x8 vv = *(const bf16x8*)(vb + (size_t)lane * ND + w * 8);
        union { bf16x8 v8; unsigned short s[8]; } u; u.v8 = vv;
        #pragma unroll
        for (int i = 0; i < 8; ++i) vt[0][w * 8 + i][lane] = u.s[i];
    }
    __syncthreads();

    int cur = 0;
    for (int tI = 0; tI < 32; ++tI) {
        const int ktn = ((tI + 1) & 31) * 64;   // wraps on last iter (harmless)
        // prefetch next tile: V rows -> regs, K fragments -> regs
        bf16x8 vv = *(const bf16x8*)(vb + (size_t)(ktn + lane) * ND + w * 8);
        #pragma unroll
        for (int f = 0; f < 4; ++f)
            kn[f] = *(const bf16x8*)(kb + (size_t)(ktn + f * 16 + l15) * ND + lhi * 8);

        // QK^T swapped: sc[f][r] = S[key=f*16+lhi*4+r][q=l15] (log2 domain)
        const f32x4 zero = {0.f, 0.f, 0.f, 0.f};
        f32x4 sc[4];
        __builtin_amdgcn_s_setprio(1);
        #pragma unroll
        for (int f = 0; f < 4; ++f)
            sc[f] = __builtin_amdgcn_mfma_f32_16x16x32_bf16(kf[f], qfrag, zero, 0, 0, 0);
        __builtin_amdgcn_s_setprio(0);

        // no-max softmax: p = 2^score, accumulate l, pack P to LDS
        #pragma unroll
        for (int f = 0; f < 4; ++f) {
            float p0 = __builtin_amdgcn_exp2f(sc[f][0]);
            float p1 = __builtin_amdgcn_exp2f(sc[f][1]);
            float p2 = __builtin_amdgcn_exp2f(sc[f][2]);
            float p3 = __builtin_amdgcn_exp2f(sc[f][3]);
            lpart += (p0 + p1) + (p2 + p3);
            union { ushort4 u; __bf16 h[4]; } pk;
            pk.h[0] = (__bf16)p0; pk.h[1] = (__bf16)p1;
            pk.h[2] = (__bf16)p2; pk.h[3] = (__bf16)p3;
            *(ushort4*)&ps[w][l15][f * 16 + lhi * 4] = pk.u;
        }

        // PV: acc[16q x 32d] += P[16q x 64k] * V[64k x 32d]
        __builtin_amdgcn_s_setprio(1);
        #pragma unroll
        for (int c = 0; c < 2; ++c) {
            bf16x8 pa  = *(const bf16x8*)&ps[w][l15][c * 32 + lhi * 8];
            bf16x8 vf0 = *(const bf16x8*)&vt[cur][l15][c * 32 + lhi * 8];
            bf16x8 vf1 = *(const bf16x8*)&vt[cur][16 + l15][c * 32 + lhi * 8];
            acc0 = __builtin_amdgcn_mfma_f32_16x16x32_bf16(pa, vf0, acc0, 0, 0, 0);
            acc1 = __builtin_amdgcn_mfma_f32_16x16x32_bf16(pa, vf1, acc1, 0, 0, 0);
        }
        __builtin_amdgcn_s_setprio(0);

        // stage prefetched V into the other buffer, rotate K regs
        {
            union { bf16x8 v8; unsigned short s[8]; } u; u.v8 = vv;
            #pragma unroll
            for (int i = 0; i < 8; ++i) vt[cur ^ 1][w * 8 + i][lane] = u.s[i];
        }
        #pragma unroll
        for (int f = 0; f < 4; ++f) kf[f] = kn[f];
        __syncthreads();
        cur ^= 1;
    }

    // final l reduction: sum the 4 lhi partials for each q=l15
    lpart += __shfl_xor(lpart, 16);
    lpart += __shfl_xor(lpart, 32);

    const int b = bh >> 3, h = bh & 7;
    #pragma unroll
    for (int r = 0; r < 4; ++r) {
        float li = __shfl(lpart, lhi * 4 + r);
        float inv = 1.0f / li;
        int row = s0 + w * 16 + lhi * 4 + r;
        unsigned short* op = ctxb + ((size_t)b * NS + row) * NF + h * ND;
        __bf16 o0 = (__bf16)(acc0[r] * inv);
        __bf16 o1 = (__bf16)(acc1[r] * inv);
        op[l15]      = *(unsigned short*)&o0;
        op[16 + l15] = *(unsigned short*)&o1;
    }
}

// ---------------------------------------------------------------------------
// Kernel 3: y = relu(ctx @ Wf + bf); z = x + y; out = LayerNorm(z).
// bf16 MFMA GEMM (32 rows x 256 cols per block, 4 waves each 64 cols),
// LN fused via LDS z-tile + wave shuffle reductions.
// ---------------------------------------------------------------------------
__global__ __launch_bounds__(256)
void dense_ln(const unsigned short* __restrict__ ctxb, const unsigned short* __restrict__ wft,
              const float* __restrict__ bfp, const float* __restrict__ x,
              float* __restrict__ out)
{
    const int r0 = blockIdx.x * 32;
    const int t = threadIdx.x;
    const int w = t >> 6;
    const int lane = t & 63;
    const int l15 = lane & 15;
    const int lhi = lane >> 4;

    __shared__ float zs[32][258];

    f32x4 acc[2][4] = {};

    for (int kt = 0; kt < NF; kt += 32) {
        bf16x8 a0 = *(const bf16x8*)(ctxb + (size_t)(r0 + l15) * NF + kt + lhi * 8);
        bf16x8 a1 = *(const bf16x8*)(ctxb + (size_t)(r0 + 16 + l15) * NF + kt + lhi * 8);
        #pragma unroll
        for (int c = 0; c < 4; ++c) {
            bf16x8 b = *(const bf16x8*)(wft + (size_t)(w * 64 + c * 16 + l15) * NF + kt + lhi * 8);
            acc[0][c] = __builtin_amdgcn_mfma_f32_16x16x32_bf16(a0, b, acc[0][c], 0, 0, 0);
            acc[1][c] = __builtin_amdgcn_mfma_f32_16x16x32_bf16(a1, b, acc[1][c], 0, 0, 0);
        }
    }

    // stage y = relu(acc + bias) into LDS
    #pragma unroll
    for (int i = 0; i < 2; ++i) {
        #pragma unroll
        for (int c = 0; c < 4; ++c) {
            const int col = w * 64 + c * 16 + l15;
            const float bb = bfp[col];
            #pragma unroll
            for (int r = 0; r < 4; ++r) {
                const int row = i * 16 + lhi * 4 + r;
                zs[row][col] = fmaxf(acc[i][c][r] + bb, 0.0f);
            }
        }
    }
    __syncthreads();

    // LN: wave w handles rows w*8 .. w*8+7; residual added here (vectorized)
    #pragma unroll
    for (int i = 0; i < 8; ++i) {
        const int row = w * 8 + i;
        float4 yv = *(const float4*)&zs[row][lane * 4];
        float4 xv = *(const float4*)(x + (size_t)(r0 + row) * NF + lane * 4);
        float z0 = xv.x + yv.x, z1 = xv.y + yv.y;
        float z2 = xv.z + yv.z, z3 = xv.w + yv.w;
        float sum = z0 + z1 + z2 + z3;
        float sq  = z0*z0 + z1*z1 + z2*z2 + z3*z3;
        #pragma unroll
        for (int o = 1; o < 64; o <<= 1) {
            sum += __shfl_xor(sum, o);
            sq  += __shfl_xor(sq, o);
        }
        float mean = sum * (1.0f / NF);
        float var  = sq * (1.0f / NF) - mean * mean;
        float rstd = rsqrtf(var + LN_EPS);
        float4 o4;
        o4.x = (z0 - mean) * rstd;
        o4.y = (z1 - mean) * rstd;
        o4.z = (z2 - mean) * rstd;
        o4.w = (z3 - mean) * rstd;
        *(float4*)(out + (size_t)(r0 + row) * NF + lane * 4) = o4;
    }
}

// ---------------------------------------------------------------------------
extern "C" void kernel_launch(void* const* d_in, const int* in_sizes, int n_in,
                              void* d_out, int out_size, void* d_ws, size_t ws_size,
                              hipStream_t stream)
{
    const float* x  = (const float*)d_in[0];
    const float* Wq = (const float*)d_in[1];
    const float* Wk = (const float*)d_in[2];
    const float* Wv = (const float*)d_in[3];
    const float* Wf = (const float*)d_in[4];
    const float* bf = (const float*)d_in[5];
    float* out = (float*)d_out;

    const size_t per = (size_t)NB * NH * NS * ND;   // 2M elements
    unsigned short* q    = (unsigned short*)d_ws;
    unsigned short* kk   = q + per;
    unsigned short* vv   = kk + per;
    unsigned short* xb   = vv + per;
    unsigned short* wt   = xb + per;                // 4 * 64K bf16 (Wq,Wk,Wv,Wf)
    unsigned short* ctxb = wt + 4 * 65536;          // bf16 [B*S][F]

    prep<<<dim3(1024 + 64), 256, 0, stream>>>(x, Wq, Wk, Wv, Wf, xb, wt);
    qkv_mfma<<<dim3(128, 3), 256, 0, stream>>>(xb, wt, q, kk, vv);
    attn_mfma<<<dim3(NB * NH, NS / 64), 256, 0, stream>>>(q, kk, vv, ctxb);
    dense_ln<<<dim3((NB * NS) / 32), 256, 0, stream>>>(ctxb, wt + 3 * 65536, bf, x, out);
}